// Round 1
// baseline (309.025 us; speedup 1.0000x reference)
//
#include <hip/hip_runtime.h>

#define Bv 32
#define Cv 64
#define Nv 1024

__device__ __forceinline__ float lrelu(float v) { return v >= 0.f ? v : 0.2f * v; }
__device__ __forceinline__ float sigmoidf(float z) { return 1.f / (1.f + __expf(-z)); }

// ---------------------------------------------------------------------------
// K1: Out[r,m] = lrelu(sum_k A[r,k] * W[m,k])   (NT GEMM, A:[M,K], W:[Nc,K])
// 64x64 tile, TK=32, 256 threads, 4x4 micro-tile, k-major LDS for b128 reads.
// ---------------------------------------------------------------------------
__global__ __launch_bounds__(256)
void gemm_nt_lrelu_kernel(const float* __restrict__ A, const float* __restrict__ W,
                          float* __restrict__ Out, int M, int Nc, int K) {
  __shared__ float As[32][68];
  __shared__ float Bs[32][68];
  const int tid = threadIdx.x;
  const int tx = tid & 15, ty = tid >> 4;
  const int row0 = blockIdx.y * 64, col0 = blockIdx.x * 64;
  float acc[4][4] = {};
  for (int k0 = 0; k0 < K; k0 += 32) {
#pragma unroll
    for (int p = 0; p < 2; ++p) {
      int r = (tid >> 3) + p * 32;
      int kk = (tid & 7) * 4;
      float4 va = *reinterpret_cast<const float4*>(&A[(size_t)(row0 + r) * K + k0 + kk]);
      float4 vb = *reinterpret_cast<const float4*>(&W[(size_t)(col0 + r) * K + k0 + kk]);
      As[kk + 0][r] = va.x; As[kk + 1][r] = va.y; As[kk + 2][r] = va.z; As[kk + 3][r] = va.w;
      Bs[kk + 0][r] = vb.x; Bs[kk + 1][r] = vb.y; Bs[kk + 2][r] = vb.z; Bs[kk + 3][r] = vb.w;
    }
    __syncthreads();
#pragma unroll
    for (int kk = 0; kk < 32; ++kk) {
      float4 a = *reinterpret_cast<const float4*>(&As[kk][ty * 4]);
      float4 b = *reinterpret_cast<const float4*>(&Bs[kk][tx * 4]);
      float av[4] = {a.x, a.y, a.z, a.w};
      float bv[4] = {b.x, b.y, b.z, b.w};
#pragma unroll
      for (int i = 0; i < 4; ++i)
#pragma unroll
        for (int j = 0; j < 4; ++j) acc[i][j] += av[i] * bv[j];
    }
    __syncthreads();
  }
#pragma unroll
  for (int i = 0; i < 4; ++i)
#pragma unroll
    for (int j = 0; j < 4; ++j)
      Out[(size_t)(row0 + ty * 4 + i) * Nc + col0 + tx * 4 + j] = lrelu(acc[i][j]);
}

// ---------------------------------------------------------------------------
// K3: energy[b,c,d] = sum_n x[b,c,n]*x[b,d,n]   (one block per batch)
// ---------------------------------------------------------------------------
__global__ __launch_bounds__(256)
void energy_kernel(const float* __restrict__ x, float* __restrict__ energy) {
  __shared__ float Xs[32][68];
  const int b = blockIdx.x;
  const float* xb = x + (size_t)b * Cv * Nv;
  const int tid = threadIdx.x, tx = tid & 15, ty = tid >> 4;
  float acc[4][4] = {};
  for (int k0 = 0; k0 < Nv; k0 += 32) {
#pragma unroll
    for (int p = 0; p < 2; ++p) {
      int r = (tid >> 3) + p * 32;
      int kk = (tid & 7) * 4;
      float4 v = *reinterpret_cast<const float4*>(&xb[(size_t)r * Nv + k0 + kk]);
      Xs[kk + 0][r] = v.x; Xs[kk + 1][r] = v.y; Xs[kk + 2][r] = v.z; Xs[kk + 3][r] = v.w;
    }
    __syncthreads();
#pragma unroll
    for (int kk = 0; kk < 32; ++kk) {
      float4 a = *reinterpret_cast<const float4*>(&Xs[kk][ty * 4]);
      float4 b = *reinterpret_cast<const float4*>(&Xs[kk][tx * 4]);
      float av[4] = {a.x, a.y, a.z, a.w};
      float bv[4] = {b.x, b.y, b.z, b.w};
#pragma unroll
      for (int i = 0; i < 4; ++i)
#pragma unroll
        for (int j = 0; j < 4; ++j) acc[i][j] += av[i] * bv[j];
    }
    __syncthreads();
  }
#pragma unroll
  for (int i = 0; i < 4; ++i)
#pragma unroll
    for (int j = 0; j < 4; ++j)
      energy[((size_t)b * Cv + ty * 4 + i) * Cv + tx * 4 + j] = acc[i][j];
}

// ---------------------------------------------------------------------------
// K4: rowmax over d, BN over (b,d) per channel c, write attention.
// One block (1 wave, 64 lanes = d) per channel c.
// ---------------------------------------------------------------------------
__global__ __launch_bounds__(64)
void bn_att_kernel(const float* __restrict__ energy, const float* __restrict__ bng,
                   const float* __restrict__ bnb, float* __restrict__ att) {
  const int c = blockIdx.x;
  const int d = threadIdx.x;
  float sum = 0.f, sumsq = 0.f;
  for (int b = 0; b < Bv; ++b) {
    float e = energy[((size_t)b * Cv + c) * Cv + d];
    float m = e;
#pragma unroll
    for (int o = 32; o > 0; o >>= 1) m = fmaxf(m, __shfl_xor(m, o));
    float v = m - e;
    sum += v; sumsq += v * v;
  }
#pragma unroll
  for (int o = 32; o > 0; o >>= 1) { sum += __shfl_xor(sum, o); sumsq += __shfl_xor(sumsq, o); }
  const float inv = 1.f / (float)(Bv * Cv);
  float mu = sum * inv;
  float var = sumsq * inv - mu * mu;
  float rs = rsqrtf(var + 1e-5f);
  float g = bng[c], be = bnb[c];
  for (int b = 0; b < Bv; ++b) {
    float e = energy[((size_t)b * Cv + c) * Cv + d];
    float m = e;
#pragma unroll
    for (int o = 32; o > 0; o >>= 1) m = fmaxf(m, __shfl_xor(m, o));
    att[((size_t)b * Cv + c) * Cv + d] = g * (m - e - mu) * rs + be;
  }
}

// ---------------------------------------------------------------------------
// chanmix: Out[b,o,n] = f( sum_k W[o,k]*In[b,k,n] , ... )
// MODE 0: Out = res + lrelu(acc + bias[o])          (static path -> x1)
// MODE 1: Out = gamma*acc + res, W per-batch (att)  (-> x_glb)
// MODE 2: Out = lrelu(acc + bias[o]), in-place ok   (final dynamic_weight)
// grid (N/64, B), 256 threads.
// ---------------------------------------------------------------------------
template <int MODE>
__global__ __launch_bounds__(256)
void chanmix_kernel(const float* __restrict__ In, const float* __restrict__ W,
                    const float* __restrict__ bias, const float* __restrict__ res,
                    const float* __restrict__ gamma_p, float* __restrict__ Out) {
  __shared__ float Wk[64][68];  // [k][o]
  __shared__ float Ts[64][68];  // [k][n]
  const int b = blockIdx.y;
  const int n0 = blockIdx.x * 64;
  const int tid = threadIdx.x, tx = tid & 15, ty = tid >> 4;
  const float* Wb = (MODE == 1) ? (W + (size_t)b * Cv * Cv) : W;
  for (int i = tid; i < 1024; i += 256) {
    int e = i * 4;
    int o = e >> 6, k = e & 63;
    float4 w4 = *reinterpret_cast<const float4*>(&Wb[e]);
    Wk[k + 0][o] = w4.x; Wk[k + 1][o] = w4.y; Wk[k + 2][o] = w4.z; Wk[k + 3][o] = w4.w;
    float4 t4 = *reinterpret_cast<const float4*>(&In[((size_t)b * Cv + o) * Nv + n0 + k]);
    *reinterpret_cast<float4*>(&Ts[o][k]) = t4;  // here o=row(k-dim of In), k=col(n)
  }
  __syncthreads();
  float acc[4][4] = {};
#pragma unroll 8
  for (int k = 0; k < 64; ++k) {
    float4 a = *reinterpret_cast<const float4*>(&Wk[k][ty * 4]);
    float4 t4 = *reinterpret_cast<const float4*>(&Ts[k][tx * 4]);
    float av[4] = {a.x, a.y, a.z, a.w};
    float tv[4] = {t4.x, t4.y, t4.z, t4.w};
#pragma unroll
    for (int i = 0; i < 4; ++i)
#pragma unroll
      for (int j = 0; j < 4; ++j) acc[i][j] += av[i] * tv[j];
  }
#pragma unroll
  for (int i = 0; i < 4; ++i) {
    int o = ty * 4 + i;
#pragma unroll
    for (int j = 0; j < 4; ++j) {
      size_t oi = ((size_t)b * Cv + o) * Nv + n0 + tx * 4 + j;
      float v = acc[i][j];
      if (MODE == 0)      v = res[oi] + lrelu(v + bias[o]);
      else if (MODE == 1) v = gamma_p[0] * v + res[oi];
      else                v = lrelu(v + bias[o]);
      Out[oi] = v;
    }
  }
}

// ---------------------------------------------------------------------------
// K6: fused dynamic graph: for m-tile of 64 columns of one batch:
//   S[n][m] = sigmoid(sum_k W_cm[n,k]*x_glb[b,k,m] + b_cm[n])
//   y1[c][m] = lrelu(sum_n x1[b,c,n]*S[n][m])  -> written to Out (d_out)
// Avoids materializing the 128MB dyn_adj.
// ---------------------------------------------------------------------------
__global__ __launch_bounds__(256)
void dyn_fused_kernel(const float* __restrict__ xglb, const float* __restrict__ x1,
                      const float* __restrict__ Wcm, const float* __restrict__ bcm,
                      float* __restrict__ Out) {
  __shared__ float XG[64][68];   // [k][m]
  __shared__ float WTk[64][68];  // [k][n]
  __shared__ float Ss[64][68];   // [n][m]
  __shared__ float X1k[64][68];  // [n][c]
  const int b = blockIdx.y;
  const int m0 = blockIdx.x * 64;
  const int tid = threadIdx.x, tx = tid & 15, ty = tid >> 4;
  for (int i = tid; i < 1024; i += 256) {
    int e = i * 4;
    int k = e >> 6, m = e & 63;
    *reinterpret_cast<float4*>(&XG[k][m]) =
        *reinterpret_cast<const float4*>(&xglb[((size_t)b * Cv + k) * Nv + m0 + m]);
  }
  float accy[4][4] = {};
  for (int n0 = 0; n0 < Nv; n0 += 64) {
    __syncthreads();  // prev accumulate done (and XG visible on first iter)
    for (int i = tid; i < 1024; i += 256) {
      int e = i * 4;
      int n = e >> 6, k = e & 63;
      float4 w4 = *reinterpret_cast<const float4*>(&Wcm[(size_t)(n0 + n) * Cv + k]);
      WTk[k + 0][n] = w4.x; WTk[k + 1][n] = w4.y; WTk[k + 2][n] = w4.z; WTk[k + 3][n] = w4.w;
      int c = e >> 6, nl = e & 63;
      float4 v4 = *reinterpret_cast<const float4*>(&x1[((size_t)b * Cv + c) * Nv + n0 + nl]);
      X1k[nl + 0][c] = v4.x; X1k[nl + 1][c] = v4.y; X1k[nl + 2][c] = v4.z; X1k[nl + 3][c] = v4.w;
    }
    __syncthreads();
    float acc[4][4] = {};
#pragma unroll 8
    for (int k = 0; k < 64; ++k) {
      float4 a = *reinterpret_cast<const float4*>(&WTk[k][ty * 4]);
      float4 g = *reinterpret_cast<const float4*>(&XG[k][tx * 4]);
      float av[4] = {a.x, a.y, a.z, a.w};
      float gv[4] = {g.x, g.y, g.z, g.w};
#pragma unroll
      for (int i = 0; i < 4; ++i)
#pragma unroll
        for (int j = 0; j < 4; ++j) acc[i][j] += av[i] * gv[j];
    }
#pragma unroll
    for (int i = 0; i < 4; ++i) {
      float bc = bcm[n0 + ty * 4 + i];
      float4 s;
      s.x = sigmoidf(acc[i][0] + bc);
      s.y = sigmoidf(acc[i][1] + bc);
      s.z = sigmoidf(acc[i][2] + bc);
      s.w = sigmoidf(acc[i][3] + bc);
      *reinterpret_cast<float4*>(&Ss[ty * 4 + i][tx * 4]) = s;
    }
    __syncthreads();
#pragma unroll 8
    for (int nn = 0; nn < 64; ++nn) {
      float4 a = *reinterpret_cast<const float4*>(&X1k[nn][ty * 4]);
      float4 s = *reinterpret_cast<const float4*>(&Ss[nn][tx * 4]);
      float av[4] = {a.x, a.y, a.z, a.w};
      float sv[4] = {s.x, s.y, s.z, s.w};
#pragma unroll
      for (int i = 0; i < 4; ++i)
#pragma unroll
        for (int j = 0; j < 4; ++j) accy[i][j] += av[i] * sv[j];
    }
  }
#pragma unroll
  for (int i = 0; i < 4; ++i)
#pragma unroll
    for (int j = 0; j < 4; ++j)
      Out[((size_t)b * Cv + ty * 4 + i) * Nv + m0 + tx * 4 + j] = lrelu(accy[i][j]);
}

extern "C" void kernel_launch(void* const* d_in, const int* in_sizes, int n_in,
                              void* d_out, int out_size, void* d_ws, size_t ws_size,
                              hipStream_t stream) {
  const float* x     = (const float*)d_in[0];
  const float* W_sa  = (const float*)d_in[1];
  const float* W_sw  = (const float*)d_in[2];
  const float* b_sw  = (const float*)d_in[3];
  const float* bn_g  = (const float*)d_in[4];
  const float* bn_b  = (const float*)d_in[5];
  const float* gamma = (const float*)d_in[6];
  const float* W_cm  = (const float*)d_in[7];
  const float* b_cm  = (const float*)d_in[8];
  const float* W_dw  = (const float*)d_in[9];
  const float* b_dw  = (const float*)d_in[10];
  float* out = (float*)d_out;

  float* ws = (float*)d_ws;
  float* t_buf    = ws;                              // 2M floats
  float* x1_buf   = ws + (size_t)2 * 1024 * 1024;    // 2M floats
  float* en_buf   = ws + (size_t)4 * 1024 * 1024;    // 128K floats
  float* att_buf  = en_buf + Bv * Cv * Cv;           // 128K floats
  float* xglb_buf = t_buf;                           // reuse (t dead after K2)

  // K1: t = lrelu(x @ W_sa^T)   [2048,1024]x[1024,1024]
  gemm_nt_lrelu_kernel<<<dim3(16, 32), 256, 0, stream>>>(x, W_sa, t_buf, Bv * Cv, Nv, Nv);
  // K2: x1 = x + lrelu(W_sw @ t + b_sw)
  chanmix_kernel<0><<<dim3(16, 32), 256, 0, stream>>>(t_buf, W_sw, b_sw, x, nullptr, x1_buf);
  // K3: energy[b] = x[b] @ x[b]^T
  energy_kernel<<<32, 256, 0, stream>>>(x, en_buf);
  // K4: attention = BN(rowmax - energy)
  bn_att_kernel<<<64, 64, 0, stream>>>(en_buf, bn_g, bn_b, att_buf);
  // K5: x_glb = gamma * (att[b] @ x[b]) + x
  chanmix_kernel<1><<<dim3(16, 32), 256, 0, stream>>>(x, att_buf, nullptr, x, gamma, xglb_buf);
  // K6: y1 = lrelu(x1 @ sigmoid(W_cm @ x_glb + b_cm))  -> d_out
  dyn_fused_kernel<<<dim3(16, 32), 256, 0, stream>>>(xglb_buf, x1_buf, W_cm, b_cm, out);
  // K7: y = lrelu(W_dw @ y1 + b_dw)  in-place on d_out
  chanmix_kernel<2><<<dim3(16, 32), 256, 0, stream>>>(out, W_dw, b_dw, nullptr, nullptr, out);
}

// Round 2
// 120.997 us; speedup vs baseline: 2.5540x; 2.5540x over previous
//
#include <hip/hip_runtime.h>

#define Bv 32
#define Cv 64
#define Nv 1024

typedef __attribute__((ext_vector_type(8))) short bf16x8;
typedef __attribute__((ext_vector_type(4))) float f32x4;
typedef __attribute__((ext_vector_type(8))) unsigned short us8;
typedef __attribute__((ext_vector_type(4))) unsigned short us4;

__device__ __forceinline__ float lrelu(float v) { return v >= 0.f ? v : 0.2f * v; }
__device__ __forceinline__ float sigmoidf_(float z) { return 1.f / (1.f + __expf(-z)); }
__device__ __forceinline__ unsigned short f2b(float f) {
  unsigned int u = __float_as_uint(f);
  unsigned int r = u + 0x7FFFu + ((u >> 16) & 1u);
  return (unsigned short)(r >> 16);
}
__device__ __forceinline__ float b2f(unsigned short u) {
  return __uint_as_float(((unsigned int)u) << 16);
}
__device__ __forceinline__ void gload16(const void* g, void* l) {
  __builtin_amdgcn_global_load_lds((const __attribute__((address_space(1))) void*)g,
                                   (__attribute__((address_space(3))) void*)l, 16, 0, 0);
}

// ---------------------------------------------------------------------------
// cvt: f32 -> bf16, 8 elems/thread
// ---------------------------------------------------------------------------
__global__ __launch_bounds__(256)
void cvt_kernel(const float* __restrict__ in, unsigned short* __restrict__ out, int n8) {
  int i = blockIdx.x * 256 + threadIdx.x;
  int stride = gridDim.x * 256;
  for (; i < n8; i += stride) {
    const float4* p = reinterpret_cast<const float4*>(in + (size_t)i * 8);
    float4 a = p[0], b = p[1];
    us8 o;
    o[0] = f2b(a.x); o[1] = f2b(a.y); o[2] = f2b(a.z); o[3] = f2b(a.w);
    o[4] = f2b(b.x); o[5] = f2b(b.y); o[6] = f2b(b.z); o[7] = f2b(b.w);
    *reinterpret_cast<us8*>(out + (size_t)i * 8) = o;
  }
}

// ---------------------------------------------------------------------------
// K1: t = lrelu(A . B^T), A=[2048][1024] bf16, B=[1024][1024] bf16 (W_sa),
// out bf16 [2048][1024]. Tile 64M x 128N, BK=64, 4 waves (2x2).
// global_load_lds w16, source pre-swizzled (kgrp ^= row&7) so fragment reads
// (which XOR the same way) are bank-conflict-free with a linear LDS dest.
// ---------------------------------------------------------------------------
__global__ __launch_bounds__(256)
void gemm_bf16_nt_lrelu(const unsigned short* __restrict__ A,
                        const unsigned short* __restrict__ B,
                        unsigned short* __restrict__ Out) {
  __shared__ __align__(16) unsigned short As[64 * 64];
  __shared__ __align__(16) unsigned short Bs[128 * 64];
  const int tid = threadIdx.x;
  const int wave = tid >> 6, lane = tid & 63;
  const int row0 = blockIdx.y * 64, col0 = blockIdx.x * 128;
  const int wr = wave >> 1, wc = wave & 1;
  f32x4 acc[2][4];
#pragma unroll
  for (int i = 0; i < 2; ++i)
#pragma unroll
    for (int j = 0; j < 4; ++j) acc[i][j] = (f32x4){0.f, 0.f, 0.f, 0.f};

  for (int k0 = 0; k0 < Nv; k0 += 64) {
#pragma unroll
    for (int i = 0; i < 2; ++i) {  // A: 64x64 = 4096 elems, 8 wave-issues
      int e0 = (wave * 2 + i) * 512;
      int row = (e0 >> 6) + (lane >> 3);
      int kk = ((lane & 7) ^ (row & 7)) << 3;  // pre-swizzled source
      gload16(&A[(size_t)(row0 + row) * Nv + k0 + kk], &As[e0]);
    }
#pragma unroll
    for (int i = 0; i < 4; ++i) {  // B: 128x64, 16 wave-issues
      int e0 = (wave * 4 + i) * 512;
      int row = (e0 >> 6) + (lane >> 3);
      int kk = ((lane & 7) ^ (row & 7)) << 3;
      gload16(&B[(size_t)(col0 + row) * Nv + k0 + kk], &Bs[e0]);
    }
    __syncthreads();
#pragma unroll
    for (int ks = 0; ks < 2; ++ks) {
      int g = ks * 4 + (lane >> 4);  // k-group 0..7
      bf16x8 af[2], bf[4];
#pragma unroll
      for (int i = 0; i < 2; ++i) {
        int row = wr * 32 + i * 16 + (lane & 15);
        af[i] = *reinterpret_cast<const bf16x8*>(&As[row * 64 + ((g ^ (row & 7)) << 3)]);
      }
#pragma unroll
      for (int j = 0; j < 4; ++j) {
        int row = wc * 64 + j * 16 + (lane & 15);
        bf[j] = *reinterpret_cast<const bf16x8*>(&Bs[row * 64 + ((g ^ (row & 7)) << 3)]);
      }
#pragma unroll
      for (int i = 0; i < 2; ++i)
#pragma unroll
        for (int j = 0; j < 4; ++j)
          acc[i][j] = __builtin_amdgcn_mfma_f32_16x16x32_bf16(af[i], bf[j], acc[i][j], 0, 0, 0);
    }
    __syncthreads();
  }
#pragma unroll
  for (int i = 0; i < 2; ++i)
#pragma unroll
    for (int j = 0; j < 4; ++j)
#pragma unroll
      for (int r = 0; r < 4; ++r) {
        int row = row0 + wr * 32 + i * 16 + (lane >> 4) * 4 + r;
        int col = col0 + wc * 64 + j * 16 + (lane & 15);
        Out[(size_t)row * Nv + col] = f2b(lrelu(acc[i][j][r]));
      }
}

// ---------------------------------------------------------------------------
// K3: energy partials: en_part[p][b][c][d] = sum_{n in p-th quarter} x[b,c,n]*x[b,d,n]
// ---------------------------------------------------------------------------
__global__ __launch_bounds__(256)
void energy_kernel(const float* __restrict__ x, float* __restrict__ en_part) {
  __shared__ float Xs[32][68];
  const int b = blockIdx.x, p = blockIdx.y;
  const float* xb = x + (size_t)b * Cv * Nv;
  const int tid = threadIdx.x, tx = tid & 15, ty = tid >> 4;
  float acc[4][4] = {};
  for (int k0 = p * 256; k0 < p * 256 + 256; k0 += 32) {
#pragma unroll
    for (int q = 0; q < 2; ++q) {
      int r = (tid >> 3) + q * 32;
      int kk = (tid & 7) * 4;
      float4 v = *reinterpret_cast<const float4*>(&xb[(size_t)r * Nv + k0 + kk]);
      Xs[kk + 0][r] = v.x; Xs[kk + 1][r] = v.y; Xs[kk + 2][r] = v.z; Xs[kk + 3][r] = v.w;
    }
    __syncthreads();
#pragma unroll
    for (int kk = 0; kk < 32; ++kk) {
      float4 a = *reinterpret_cast<const float4*>(&Xs[kk][ty * 4]);
      float4 c = *reinterpret_cast<const float4*>(&Xs[kk][tx * 4]);
      float av[4] = {a.x, a.y, a.z, a.w};
      float cv[4] = {c.x, c.y, c.z, c.w};
#pragma unroll
      for (int i = 0; i < 4; ++i)
#pragma unroll
        for (int j = 0; j < 4; ++j) acc[i][j] += av[i] * cv[j];
    }
    __syncthreads();
  }
#pragma unroll
  for (int i = 0; i < 4; ++i)
#pragma unroll
    for (int j = 0; j < 4; ++j)
      en_part[((size_t)p * Bv + b) * 4096 + (size_t)(ty * 4 + i) * 64 + tx * 4 + j] = acc[i][j];
}

// ---------------------------------------------------------------------------
// K4: attention = BN(rowmax - energy) over (b, d) per channel c. 1 wave/channel.
// energy comes in 4 partial slabs of stride 32*4096.
// ---------------------------------------------------------------------------
__global__ __launch_bounds__(64)
void bn_att_kernel(const float* __restrict__ en, const float* __restrict__ bng,
                   const float* __restrict__ bnb, float* __restrict__ att) {
  const int c = blockIdx.x;
  const int d = threadIdx.x;
  const size_t PS = (size_t)Bv * 4096;
  float sum = 0.f, sumsq = 0.f;
  for (int b = 0; b < Bv; ++b) {
    size_t base = (size_t)b * 4096 + (size_t)c * 64 + d;
    float e = en[base] + en[base + PS] + en[base + 2 * PS] + en[base + 3 * PS];
    float m = e;
#pragma unroll
    for (int o = 32; o > 0; o >>= 1) m = fmaxf(m, __shfl_xor(m, o));
    float v = m - e;
    sum += v; sumsq += v * v;
  }
#pragma unroll
  for (int o = 32; o > 0; o >>= 1) { sum += __shfl_xor(sum, o); sumsq += __shfl_xor(sumsq, o); }
  const float inv = 1.f / (float)(Bv * Cv);
  float mu = sum * inv;
  float var = sumsq * inv - mu * mu;
  float rs = rsqrtf(var + 1e-5f);
  float g = bng[c], be = bnb[c];
  for (int b = 0; b < Bv; ++b) {
    size_t base = (size_t)b * 4096 + (size_t)c * 64 + d;
    float e = en[base] + en[base + PS] + en[base + 2 * PS] + en[base + 3 * PS];
    float m = e;
#pragma unroll
    for (int o = 32; o > 0; o >>= 1) m = fmaxf(m, __shfl_xor(m, o));
    att[(size_t)b * 4096 + (size_t)c * 64 + d] = g * (m - e - mu) * rs + be;
  }
}

// ---------------------------------------------------------------------------
// chanmix: Out[b,o,n] = f( sum_k W[o,k]*In[b,k,n] )
// MODE 0: In bf16 (t), Out bf16 = f2b(res + lrelu(acc+bias))   -> x1
// MODE 1: In f32 (x), W per-batch att, Out bf16 = gamma*acc+res -> x_glb
// MODE 2: In f32, Out f32 = lrelu(acc+bias), in-place            -> final y
// ---------------------------------------------------------------------------
template <int MODE>
__global__ __launch_bounds__(256)
void chanmix_kernel(const void* __restrict__ In_, const float* __restrict__ W,
                    const float* __restrict__ bias, const float* __restrict__ res,
                    const float* __restrict__ gamma_p, void* __restrict__ Out_) {
  __shared__ float Wk[64][68];  // [k][o]
  __shared__ float Ts[64][68];  // [k_in][n]
  const int b = blockIdx.y;
  const int n0 = blockIdx.x * 64;
  const int tid = threadIdx.x, tx = tid & 15, ty = tid >> 4;
  const float* Wb = (MODE == 1) ? (W + (size_t)b * Cv * Cv) : W;
  for (int i = tid; i < 1024; i += 256) {
    int e = i * 4;
    int o = e >> 6, k = e & 63;
    float4 w4 = *reinterpret_cast<const float4*>(&Wb[e]);
    Wk[k + 0][o] = w4.x; Wk[k + 1][o] = w4.y; Wk[k + 2][o] = w4.z; Wk[k + 3][o] = w4.w;
    if (MODE == 0) {
      const unsigned short* In = (const unsigned short*)In_;
      us4 t4 = *reinterpret_cast<const us4*>(&In[((size_t)b * Cv + o) * Nv + n0 + k]);
      Ts[o][k + 0] = b2f(t4[0]); Ts[o][k + 1] = b2f(t4[1]);
      Ts[o][k + 2] = b2f(t4[2]); Ts[o][k + 3] = b2f(t4[3]);
    } else {
      const float* In = (const float*)In_;
      float4 t4 = *reinterpret_cast<const float4*>(&In[((size_t)b * Cv + o) * Nv + n0 + k]);
      *reinterpret_cast<float4*>(&Ts[o][k]) = t4;
    }
  }
  __syncthreads();
  float acc[4][4] = {};
#pragma unroll 8
  for (int k = 0; k < 64; ++k) {
    float4 a = *reinterpret_cast<const float4*>(&Wk[k][ty * 4]);
    float4 t4 = *reinterpret_cast<const float4*>(&Ts[k][tx * 4]);
    float av[4] = {a.x, a.y, a.z, a.w};
    float tv[4] = {t4.x, t4.y, t4.z, t4.w};
#pragma unroll
    for (int i = 0; i < 4; ++i)
#pragma unroll
      for (int j = 0; j < 4; ++j) acc[i][j] += av[i] * tv[j];
  }
#pragma unroll
  for (int i = 0; i < 4; ++i) {
    int o = ty * 4 + i;
#pragma unroll
    for (int j = 0; j < 4; ++j) {
      size_t oi = ((size_t)b * Cv + o) * Nv + n0 + tx * 4 + j;
      float v = acc[i][j];
      if (MODE == 0) {
        v = res[oi] + lrelu(v + bias[o]);
        ((unsigned short*)Out_)[oi] = f2b(v);
      } else if (MODE == 1) {
        v = gamma_p[0] * v + res[oi];
        ((unsigned short*)Out_)[oi] = f2b(v);
      } else {
        v = lrelu(v + bias[o]);
        ((float*)Out_)[oi] = v;
      }
    }
  }
}

// ---------------------------------------------------------------------------
// K6: fused dynamic graph, bf16 MFMA. Per block (b, 64-col m-tile):
//   stage1: S[n][m] = sigmoid(W_cm[n,:] . xglb[b,:,m] + b_cm[n])  (MFMA, per 64-n chunk)
//   stage2: y[c][m] += x1[b,c,nchunk] . S[nchunk][m]              (MFMA)
// All LDS tiles padded to stride 72 (bank-conflict-free b128 reads).
// ---------------------------------------------------------------------------
__global__ __launch_bounds__(256)
void dyn_fused_mfma(const unsigned short* __restrict__ xglbB,
                    const unsigned short* __restrict__ x1B,
                    const unsigned short* __restrict__ WcmB,
                    const float* __restrict__ bcm, float* __restrict__ Out) {
  __shared__ __align__(16) unsigned short XT[64 * 72];  // [m][k]
  __shared__ __align__(16) unsigned short WT[64 * 72];  // [n][k]
  __shared__ __align__(16) unsigned short X1[64 * 72];  // [c][n]
  __shared__ __align__(16) unsigned short SB[64 * 72];  // [m][n]
  const int b = blockIdx.y, m0 = blockIdx.x * 64;
  const int tid = threadIdx.x, wave = tid >> 6, lane = tid & 63;

  {  // XT: transpose xglb[b][k][m-tile] -> [m][k]
    int k = tid >> 2, mo = (tid & 3) * 16;
    const us8* src = reinterpret_cast<const us8*>(xglbB + ((size_t)b * Cv + k) * Nv + m0 + mo);
    us8 v0 = src[0], v1 = src[1];
#pragma unroll
    for (int mi = 0; mi < 8; ++mi) XT[(mo + mi) * 72 + k] = v0[mi];
#pragma unroll
    for (int mi = 0; mi < 8; ++mi) XT[(mo + 8 + mi) * 72 + k] = v1[mi];
  }
  f32x4 accy[4];
#pragma unroll
  for (int j = 0; j < 4; ++j) accy[j] = (f32x4){0.f, 0.f, 0.f, 0.f};

  for (int n0 = 0; n0 < Nv; n0 += 64) {
    {  // stage WT [n][k] and X1 [c][n], padded rows
      int rr = tid >> 2, off = (tid & 3) * 16;
      const us8* wsrc = reinterpret_cast<const us8*>(WcmB + (size_t)(n0 + rr) * Cv + off);
      us8 w0 = wsrc[0], w1 = wsrc[1];
      *reinterpret_cast<us8*>(&WT[rr * 72 + off]) = w0;
      *reinterpret_cast<us8*>(&WT[rr * 72 + off + 8]) = w1;
      const us8* xsrc = reinterpret_cast<const us8*>(x1B + ((size_t)b * Cv + rr) * Nv + n0 + off);
      us8 x0 = xsrc[0], x1v = xsrc[1];
      *reinterpret_cast<us8*>(&X1[rr * 72 + off]) = x0;
      *reinterpret_cast<us8*>(&X1[rr * 72 + off + 8]) = x1v;
    }
    __syncthreads();  // staging (and XT on first iter) visible
    // stage 1: rows n = n0 + wave*16 + frag-rows ; cols m
    f32x4 s1[4];
#pragma unroll
    for (int j = 0; j < 4; ++j) s1[j] = (f32x4){0.f, 0.f, 0.f, 0.f};
#pragma unroll
    for (int ks = 0; ks < 2; ++ks) {
      int kg = ks * 32 + (lane >> 4) * 8;
      bf16x8 wf = *reinterpret_cast<const bf16x8*>(&WT[(wave * 16 + (lane & 15)) * 72 + kg]);
#pragma unroll
      for (int j = 0; j < 4; ++j) {
        bf16x8 xf = *reinterpret_cast<const bf16x8*>(&XT[(j * 16 + (lane & 15)) * 72 + kg]);
        s1[j] = __builtin_amdgcn_mfma_f32_16x16x32_bf16(wf, xf, s1[j], 0, 0, 0);
      }
    }
    // sigmoid + transpose-store to SB[m][n]
    float4 bc = *reinterpret_cast<const float4*>(&bcm[n0 + wave * 16 + (lane >> 4) * 4]);
    float bcr[4] = {bc.x, bc.y, bc.z, bc.w};
#pragma unroll
    for (int j = 0; j < 4; ++j) {
      us4 sv;
#pragma unroll
      for (int r = 0; r < 4; ++r) sv[r] = f2b(sigmoidf_(s1[j][r] + bcr[r]));
      *reinterpret_cast<us4*>(&SB[(j * 16 + (lane & 15)) * 72 + wave * 16 + (lane >> 4) * 4]) = sv;
    }
    __syncthreads();  // SB ready
    // stage 2: y[c][m] += x1 . S  (contract this chunk's 64 n)
#pragma unroll
    for (int ks = 0; ks < 2; ++ks) {
      int kg = ks * 32 + (lane >> 4) * 8;
      bf16x8 a2 = *reinterpret_cast<const bf16x8*>(&X1[(wave * 16 + (lane & 15)) * 72 + kg]);
#pragma unroll
      for (int j = 0; j < 4; ++j) {
        bf16x8 b2 = *reinterpret_cast<const bf16x8*>(&SB[(j * 16 + (lane & 15)) * 72 + kg]);
        accy[j] = __builtin_amdgcn_mfma_f32_16x16x32_bf16(a2, b2, accy[j], 0, 0, 0);
      }
    }
    __syncthreads();  // protect WT/X1/SB before next chunk staging
  }
#pragma unroll
  for (int j = 0; j < 4; ++j)
#pragma unroll
    for (int r = 0; r < 4; ++r) {
      int c = wave * 16 + (lane >> 4) * 4 + r;
      Out[((size_t)b * Cv + c) * Nv + m0 + j * 16 + (lane & 15)] = lrelu(accy[j][r]);
    }
}

extern "C" void kernel_launch(void* const* d_in, const int* in_sizes, int n_in,
                              void* d_out, int out_size, void* d_ws, size_t ws_size,
                              hipStream_t stream) {
  const float* x     = (const float*)d_in[0];
  const float* W_sa  = (const float*)d_in[1];
  const float* W_sw  = (const float*)d_in[2];
  const float* b_sw  = (const float*)d_in[3];
  const float* bn_g  = (const float*)d_in[4];
  const float* bn_b  = (const float*)d_in[5];
  const float* gamma = (const float*)d_in[6];
  const float* W_cm  = (const float*)d_in[7];
  const float* b_cm  = (const float*)d_in[8];
  const float* W_dw  = (const float*)d_in[9];
  const float* b_dw  = (const float*)d_in[10];
  float* out = (float*)d_out;

  char* ws = (char*)d_ws;
  const size_t ACT = (size_t)Bv * Cv * Nv;  // 2M elems
  unsigned short* tB     = (unsigned short*)ws;               ws += ACT * 2;       // 4MB
  unsigned short* xb     = (unsigned short*)ws;               ws += ACT * 2;       // 4MB
  unsigned short* x1b    = (unsigned short*)ws;               ws += ACT * 2;       // 4MB
  unsigned short* xglbB  = (unsigned short*)ws;               ws += ACT * 2;       // 4MB
  unsigned short* WsaB   = (unsigned short*)ws;               ws += (size_t)Nv * Nv * 2;  // 2MB
  unsigned short* WcmB   = (unsigned short*)ws;               ws += (size_t)Nv * Cv * 2;  // 128KB
  float* en_part         = (float*)ws;                        ws += (size_t)4 * Bv * 4096 * 4;  // 2MB
  float* att_buf         = (float*)ws;                        ws += (size_t)Bv * 4096 * 4;      // 512KB

  // conversions
  cvt_kernel<<<1024, 256, 0, stream>>>(x, xb, (int)(ACT / 8));
  cvt_kernel<<<512, 256, 0, stream>>>(W_sa, WsaB, Nv * Nv / 8);
  cvt_kernel<<<32, 256, 0, stream>>>(W_cm, WcmB, Nv * Cv / 8);
  // K1: t = lrelu(x @ W_sa^T)  (bf16 MFMA)
  gemm_bf16_nt_lrelu<<<dim3(8, 32), 256, 0, stream>>>(xb, WsaB, tB);
  // K2: x1 = x + lrelu(W_sw @ t + b_sw)  -> bf16
  chanmix_kernel<0><<<dim3(16, Bv), 256, 0, stream>>>(tB, W_sw, b_sw, x, nullptr, x1b);
  // K3: energy partials
  energy_kernel<<<dim3(Bv, 4), 256, 0, stream>>>(x, en_part);
  // K4: attention = BN(rowmax - energy)
  bn_att_kernel<<<Cv, 64, 0, stream>>>(en_part, bn_g, bn_b, att_buf);
  // K5: x_glb = gamma*(att @ x) + x  -> bf16
  chanmix_kernel<1><<<dim3(16, Bv), 256, 0, stream>>>(x, att_buf, nullptr, x, gamma, xglbB);
  // K6: y1 = lrelu(x1 @ sigmoid(W_cm @ x_glb + b_cm))  (bf16 MFMA) -> d_out (f32)
  dyn_fused_mfma<<<dim3(16, Bv), 256, 0, stream>>>(xglbB, x1b, WcmB, b_cm, out);
  // K7: y = lrelu(W_dw @ y1 + b_dw) in-place
  chanmix_kernel<2><<<dim3(16, Bv), 256, 0, stream>>>(out, W_dw, b_dw, nullptr, nullptr, out);
}

// Round 3
// 101.133 us; speedup vs baseline: 3.0556x; 1.1964x over previous
//
#include <hip/hip_runtime.h>

#define Bv 32
#define Cv 64
#define Nv 1024

typedef __attribute__((ext_vector_type(8))) short bf16x8;
typedef __attribute__((ext_vector_type(4))) float f32x4;
typedef __attribute__((ext_vector_type(8))) unsigned short us8;
typedef __attribute__((ext_vector_type(4))) unsigned short us4;

__device__ __forceinline__ float lrelu(float v) { return v >= 0.f ? v : 0.2f * v; }
__device__ __forceinline__ float sigmoidf_(float z) { return 1.f / (1.f + __expf(-z)); }
__device__ __forceinline__ unsigned short f2b(float f) {
  unsigned int u = __float_as_uint(f);
  unsigned int r = u + 0x7FFFu + ((u >> 16) & 1u);
  return (unsigned short)(r >> 16);
}
__device__ __forceinline__ void gload16(const void* g, void* l) {
  __builtin_amdgcn_global_load_lds((const __attribute__((address_space(1))) void*)g,
                                   (__attribute__((address_space(3))) void*)l, 16, 0, 0);
}
// LDS tile layout: 64 rows x 64 bf16 (128B/row = 8 granules of 16B).
// Granule g of row r holds global granule g ^ (r&7). Frag read applies same XOR.
__device__ __forceinline__ bf16x8 fragr(const unsigned short* buf, int row, int ks, int lane) {
  return *reinterpret_cast<const bf16x8*>(
      &buf[row * 64 + (((ks * 4 + (lane >> 4)) ^ (row & 7)) << 3)]);
}

// ---------------------------------------------------------------------------
// prep: all f32->bf16 conversions + xT transpose, one launch.
// blocks: [0,1024) xb | [1024,1536) xbT | [1536,2048) W_sa | [2048,2080) W_cm
//         [2080,2082) W_sw | [2082,2084) W_dw
// ---------------------------------------------------------------------------
__device__ __forceinline__ void cvt8(const float* in, unsigned short* out, int i) {
  const f32x4* p = reinterpret_cast<const f32x4*>(in + (size_t)i * 8);
  f32x4 a = p[0], b = p[1];
  us8 o;
  o[0] = f2b(a[0]); o[1] = f2b(a[1]); o[2] = f2b(a[2]); o[3] = f2b(a[3]);
  o[4] = f2b(b[0]); o[5] = f2b(b[1]); o[6] = f2b(b[2]); o[7] = f2b(b[3]);
  *reinterpret_cast<us8*>(out + (size_t)i * 8) = o;
}

__global__ __launch_bounds__(256)
void prep_kernel(const float* __restrict__ x, const float* __restrict__ Wsa,
                 const float* __restrict__ Wcm, const float* __restrict__ Wsw,
                 const float* __restrict__ Wdw, unsigned short* __restrict__ xb,
                 unsigned short* __restrict__ xbT, unsigned short* __restrict__ WsaB,
                 unsigned short* __restrict__ WcmB, unsigned short* __restrict__ WswB,
                 unsigned short* __restrict__ WdwB) {
  __shared__ unsigned short L[64 * 72];
  const int blk = blockIdx.x, tid = threadIdx.x;
  if (blk < 1024) {
    cvt8(x, xb, blk * 256 + tid);
  } else if (blk < 1536) {
    int id = blk - 1024;
    int b = id >> 4, n0 = (id & 15) * 64;
    int c = tid >> 2, nseg = (tid & 3) * 16;
    const float* src = &x[((size_t)(b * 64 + c) << 10) + n0 + nseg];
#pragma unroll
    for (int q = 0; q < 4; ++q) {
      f32x4 v = *reinterpret_cast<const f32x4*>(src + q * 4);
#pragma unroll
      for (int e = 0; e < 4; ++e) L[(nseg + q * 4 + e) * 72 + c] = f2b(v[e]);
    }
    __syncthreads();
    int n = tid >> 2, cs = (tid & 3) * 16;
    us8 a = *reinterpret_cast<const us8*>(&L[n * 72 + cs]);
    us8 bq = *reinterpret_cast<const us8*>(&L[n * 72 + cs + 8]);
    unsigned short* dst = &xbT[(((size_t)b << 10) + n0 + n) * 64 + cs];
    *reinterpret_cast<us8*>(dst) = a;
    *reinterpret_cast<us8*>(dst + 8) = bq;
  } else if (blk < 2048) {
    cvt8(Wsa, WsaB, (blk - 1536) * 256 + tid);
  } else if (blk < 2080) {
    cvt8(Wcm, WcmB, (blk - 2048) * 256 + tid);
  } else if (blk < 2082) {
    cvt8(Wsw, WswB, (blk - 2080) * 256 + tid);
  } else {
    cvt8(Wdw, WdwB, (blk - 2082) * 256 + tid);
  }
}

// ---------------------------------------------------------------------------
// K1: tT[b][n][c] = lrelu(sum_k xb[b*64+c][k] * Wsa[n][k])  (NT GEMM, MFMA)
// grid (16 n-tiles, 32 b), 4 waves 2x2, BK=64.
// ---------------------------------------------------------------------------
__global__ __launch_bounds__(256)
void k1_gemm(const unsigned short* __restrict__ xb, const unsigned short* __restrict__ WsaB,
             unsigned short* __restrict__ tT) {
  __shared__ unsigned short As[4096], Bs[4096];
  const int tid = threadIdx.x, wave = tid >> 6, lane = tid & 63;
  const int b = blockIdx.y, col0 = blockIdx.x * 64, row0 = b * 64;
  const int wr = wave >> 1, wc = wave & 1;
  f32x4 acc[2][2];
#pragma unroll
  for (int i = 0; i < 2; ++i)
#pragma unroll
    for (int j = 0; j < 2; ++j) acc[i][j] = (f32x4){0.f, 0.f, 0.f, 0.f};
  for (int k0 = 0; k0 < Nv; k0 += 64) {
#pragma unroll
    for (int p = 0; p < 2; ++p) {
      int q = wave * 2 + p;
      int rr = q * 8 + (lane >> 3);
      int gS = ((lane & 7) ^ (rr & 7)) << 3;
      gload16(&xb[(size_t)(row0 + rr) * Nv + k0 + gS], &As[q * 512]);
      gload16(&WsaB[(size_t)(col0 + rr) * Nv + k0 + gS], &Bs[q * 512]);
    }
    __syncthreads();
#pragma unroll
    for (int ks = 0; ks < 2; ++ks) {
      bf16x8 af[2], bfg[2];
#pragma unroll
      for (int i = 0; i < 2; ++i) af[i] = fragr(As, wr * 32 + i * 16 + (lane & 15), ks, lane);
#pragma unroll
      for (int j = 0; j < 2; ++j) bfg[j] = fragr(Bs, wc * 32 + j * 16 + (lane & 15), ks, lane);
#pragma unroll
      for (int i = 0; i < 2; ++i)
#pragma unroll
        for (int j = 0; j < 2; ++j)
          acc[i][j] = __builtin_amdgcn_mfma_f32_16x16x32_bf16(af[i], bfg[j], acc[i][j], 0, 0, 0);
    }
    __syncthreads();
  }
#pragma unroll
  for (int i = 0; i < 2; ++i)
#pragma unroll
    for (int j = 0; j < 2; ++j) {
      int n = col0 + wc * 32 + j * 16 + (lane & 15);
      int c = wr * 32 + i * 16 + (lane >> 4) * 4;
      us4 sv;
#pragma unroll
      for (int r = 0; r < 4; ++r) sv[r] = f2b(lrelu(acc[i][j][r]));
      *reinterpret_cast<us4*>(&tT[(((size_t)b << 10) + n) * 64 + c]) = sv;
    }
}

// ---------------------------------------------------------------------------
// chanmix (MFMA): acc[o][n] = sum_c A[o][c] * Bsrc[b][n][c]   (K=64)
// MODE 0: x1[b][o][n] = x + lrelu(acc + bias[o])        (A=W_sw)
// MODE 1: xglbT[b][n][o] = gamma*acc + x                (A=att[b])
// ---------------------------------------------------------------------------
template <int MODE>
__global__ __launch_bounds__(256)
void chanmix_mfma(const unsigned short* __restrict__ Bsrc, const unsigned short* __restrict__ Aw,
                  const float* __restrict__ x, const float* __restrict__ bias,
                  const float* __restrict__ gamma_p, unsigned short* __restrict__ out) {
  __shared__ unsigned short Bs[4096];
  __shared__ float Xres[64][68];
  const int tid = threadIdx.x, wave = tid >> 6, lane = tid & 63;
  const int b = blockIdx.y, n0 = blockIdx.x * 64;
  const unsigned short* Ab = (MODE == 1) ? (Aw + (size_t)b * 4096) : Aw;
  bf16x8 af[2];
#pragma unroll
  for (int ks = 0; ks < 2; ++ks)
    af[ks] = *reinterpret_cast<const bf16x8*>(
        &Ab[(wave * 16 + (lane & 15)) * 64 + ks * 32 + (lane >> 4) * 8]);
#pragma unroll
  for (int p = 0; p < 2; ++p) {
    int q = wave * 2 + p;
    int rr = q * 8 + (lane >> 3);
    int gS = ((lane & 7) ^ (rr & 7)) << 3;
    gload16(&Bsrc[(((size_t)b << 10) + n0 + rr) * 64 + gS], &Bs[q * 512]);
  }
  {
    int o = tid >> 2, c0 = (tid & 3) * 16;
    const float* xs = &x[((size_t)(b * 64 + o) << 10) + n0 + c0];
#pragma unroll
    for (int q = 0; q < 4; ++q)
      *reinterpret_cast<f32x4*>(&Xres[o][c0 + q * 4]) = *reinterpret_cast<const f32x4*>(xs + q * 4);
  }
  __syncthreads();
  f32x4 acc[4];
#pragma unroll
  for (int j = 0; j < 4; ++j) acc[j] = (f32x4){0.f, 0.f, 0.f, 0.f};
#pragma unroll
  for (int ks = 0; ks < 2; ++ks)
#pragma unroll
    for (int j = 0; j < 4; ++j) {
      bf16x8 bfr = fragr(Bs, j * 16 + (lane & 15), ks, lane);
      acc[j] = __builtin_amdgcn_mfma_f32_16x16x32_bf16(af[ks], bfr, acc[j], 0, 0, 0);
    }
  float g0 = (MODE == 1) ? gamma_p[0] : 0.f;
#pragma unroll
  for (int j = 0; j < 4; ++j) {
    int nl = j * 16 + (lane & 15);
    if (MODE == 0) {
#pragma unroll
      for (int r = 0; r < 4; ++r) {
        int o = wave * 16 + (lane >> 4) * 4 + r;
        float v = Xres[o][nl] + lrelu(acc[j][r] + bias[o]);
        out[((size_t)(b * 64 + o) << 10) + n0 + nl] = f2b(v);
      }
    } else {
      us4 sv;
#pragma unroll
      for (int r = 0; r < 4; ++r) {
        int o = wave * 16 + (lane >> 4) * 4 + r;
        sv[r] = f2b(g0 * acc[j][r] + Xres[o][nl]);
      }
      *reinterpret_cast<us4*>(
          &out[(((size_t)b << 10) + n0 + nl) * 64 + wave * 16 + (lane >> 4) * 4]) = sv;
    }
  }
}

// ---------------------------------------------------------------------------
// energy (MFMA): en[b][c][d] = sum_n x[b,c,n]*x[b,d,n], f32 accum out.
// One block per batch; staging converts f32->bf16 inline.
// ---------------------------------------------------------------------------
__global__ __launch_bounds__(256)
void energy_mfma(const float* __restrict__ x, float* __restrict__ en) {
  __shared__ unsigned short Xs[4096];
  const int tid = threadIdx.x, wave = tid >> 6, lane = tid & 63;
  const int b = blockIdx.x;
  f32x4 acc[4];
#pragma unroll
  for (int j = 0; j < 4; ++j) acc[j] = (f32x4){0.f, 0.f, 0.f, 0.f};
  for (int k0 = 0; k0 < Nv; k0 += 64) {
    __syncthreads();
    {
      int rr = tid >> 2, c0 = (tid & 3) * 16;
      const float* src = &x[((size_t)(b * 64 + rr) << 10) + k0 + c0];
#pragma unroll
      for (int h = 0; h < 2; ++h) {
        us8 pk;
#pragma unroll
        for (int q = 0; q < 2; ++q) {
          f32x4 v = *reinterpret_cast<const f32x4*>(src + h * 8 + q * 4);
#pragma unroll
          for (int e = 0; e < 4; ++e) pk[q * 4 + e] = f2b(v[e]);
        }
        *reinterpret_cast<us8*>(&Xs[rr * 64 + ((((c0 >> 3) + h) ^ (rr & 7)) << 3)]) = pk;
      }
    }
    __syncthreads();
#pragma unroll
    for (int ks = 0; ks < 2; ++ks) {
      bf16x8 a = fragr(Xs, wave * 16 + (lane & 15), ks, lane);
#pragma unroll
      for (int j = 0; j < 4; ++j) {
        bf16x8 bfr = fragr(Xs, j * 16 + (lane & 15), ks, lane);
        acc[j] = __builtin_amdgcn_mfma_f32_16x16x32_bf16(a, bfr, acc[j], 0, 0, 0);
      }
    }
  }
#pragma unroll
  for (int j = 0; j < 4; ++j)
#pragma unroll
    for (int r = 0; r < 4; ++r)
      en[((size_t)(b * 64) + wave * 16 + (lane >> 4) * 4 + r) * 64 + j * 16 + (lane & 15)] =
          acc[j][r];
}

// ---------------------------------------------------------------------------
// bn_att: attention = BN(rowmax(en) - en), output bf16. 1 wave per channel c.
// ---------------------------------------------------------------------------
__global__ __launch_bounds__(64)
void bn_att_kernel(const float* __restrict__ en, const float* __restrict__ bng,
                   const float* __restrict__ bnb, unsigned short* __restrict__ att) {
  const int c = blockIdx.x, d = threadIdx.x;
  float sum = 0.f, sumsq = 0.f;
  for (int b = 0; b < Bv; ++b) {
    float e = en[((size_t)b * Cv + c) * Cv + d];
    float m = e;
#pragma unroll
    for (int o = 32; o > 0; o >>= 1) m = fmaxf(m, __shfl_xor(m, o));
    float v = m - e;
    sum += v; sumsq += v * v;
  }
#pragma unroll
  for (int o = 32; o > 0; o >>= 1) { sum += __shfl_xor(sum, o); sumsq += __shfl_xor(sumsq, o); }
  const float inv = 1.f / (float)(Bv * Cv);
  float mu = sum * inv;
  float var = sumsq * inv - mu * mu;
  float rs = rsqrtf(var + 1e-5f);
  float g = bng[c], be = bnb[c];
  for (int b = 0; b < Bv; ++b) {
    float e = en[((size_t)b * Cv + c) * Cv + d];
    float m = e;
#pragma unroll
    for (int o = 32; o > 0; o >>= 1) m = fmaxf(m, __shfl_xor(m, o));
    att[((size_t)b * Cv + c) * Cv + d] = f2b(g * (m - e - mu) * rs + be);
  }
}

// ---------------------------------------------------------------------------
// dyn: per (m-tile, b, ns): ypart[ns][b][m][c] = sum_{n in half}
//        x1[b][c][n] * sigmoid(Wcm[n][:].xglb[:][m] + bcm[n])
// Waves own private 16-m columns -> S in private LDS strip, no S barriers.
// ---------------------------------------------------------------------------
__global__ __launch_bounds__(256)
void dyn_fused(const unsigned short* __restrict__ xglbT, const unsigned short* __restrict__ x1b,
               const unsigned short* __restrict__ WcmB, const float* __restrict__ bcm,
               float* __restrict__ ypart) {
  __shared__ unsigned short WT[4096], X1[4096];
  __shared__ unsigned short SBt[4 * 16 * 72];
  const int tid = threadIdx.x, wave = tid >> 6, lane = tid & 63;
  const int m0 = blockIdx.x * 64, b = blockIdx.y, ns = blockIdx.z;
  const int nbase = ns * 512;
  bf16x8 xgf[2];
#pragma unroll
  for (int ks = 0; ks < 2; ++ks)
    xgf[ks] = *reinterpret_cast<const bf16x8*>(
        &xglbT[(((size_t)b << 10) + m0 + wave * 16 + (lane & 15)) * 64 + ks * 32 + (lane >> 4) * 8]);
  f32x4 accy[4];
#pragma unroll
  for (int j = 0; j < 4; ++j) accy[j] = (f32x4){0.f, 0.f, 0.f, 0.f};
  unsigned short* SB = &SBt[wave * 16 * 72];
  for (int ch = 0; ch < 8; ++ch) {
    const int n0 = nbase + ch * 64;
    __syncthreads();
#pragma unroll
    for (int p = 0; p < 2; ++p) {
      int q = wave * 2 + p;
      int rr = q * 8 + (lane >> 3);
      int gS = ((lane & 7) ^ (rr & 7)) << 3;
      gload16(&WcmB[(size_t)(n0 + rr) * 64 + gS], &WT[q * 512]);
      gload16(&x1b[((size_t)(b * 64 + rr) << 10) + n0 + gS], &X1[q * 512]);
    }
    __syncthreads();
    // stage1: S rows n (4 tiles), cols = wave's 16 m
#pragma unroll
    for (int i = 0; i < 4; ++i) {
      f32x4 s = (f32x4){0.f, 0.f, 0.f, 0.f};
#pragma unroll
      for (int ks = 0; ks < 2; ++ks) {
        bf16x8 af = fragr(WT, i * 16 + (lane & 15), ks, lane);
        s = __builtin_amdgcn_mfma_f32_16x16x32_bf16(af, xgf[ks], s, 0, 0, 0);
      }
      f32x4 bc4 = *reinterpret_cast<const f32x4*>(&bcm[n0 + i * 16 + (lane >> 4) * 4]);
      us4 sv;
#pragma unroll
      for (int r = 0; r < 4; ++r) sv[r] = f2b(sigmoidf_(s[r] + bc4[r]));
      *reinterpret_cast<us4*>(&SB[(lane & 15) * 72 + i * 16 + (lane >> 4) * 4]) = sv;
    }
    // stage2: accy[c-tile] += x1 . S
#pragma unroll
    for (int ks = 0; ks < 2; ++ks) {
      bf16x8 b2 = *reinterpret_cast<const bf16x8*>(
          &SB[(lane & 15) * 72 + ks * 32 + (lane >> 4) * 8]);
#pragma unroll
      for (int jc = 0; jc < 4; ++jc) {
        bf16x8 a2 = fragr(X1, jc * 16 + (lane & 15), ks, lane);
        accy[jc] = __builtin_amdgcn_mfma_f32_16x16x32_bf16(a2, b2, accy[jc], 0, 0, 0);
      }
    }
  }
#pragma unroll
  for (int jc = 0; jc < 4; ++jc)
    *reinterpret_cast<f32x4*>(
        &ypart[(((size_t)(ns * 32 + b) << 10) + m0 + wave * 16 + (lane & 15)) * 64 + jc * 16 +
               (lane >> 4) * 4]) = accy[jc];
}

// ---------------------------------------------------------------------------
// final: y[b][o][n] = lrelu(sum_c Wdw[o][c] * y1[n][c] + bdw[o]),
//   y1[n][c] = lrelu(ypart0 + ypart1). Swapped-operand MFMA: D[n][o].
// ---------------------------------------------------------------------------
__global__ __launch_bounds__(256)
void final_gemm(const float* __restrict__ ypart, const unsigned short* __restrict__ WdwB,
                const float* __restrict__ bdw, float* __restrict__ dout) {
  __shared__ unsigned short YT[4096];
  const int tid = threadIdx.x, wave = tid >> 6, lane = tid & 63;
  const int b = blockIdx.y, n0 = blockIdx.x * 64;
  bf16x8 bw[4][2];
#pragma unroll
  for (int jo = 0; jo < 4; ++jo)
#pragma unroll
    for (int ks = 0; ks < 2; ++ks)
      bw[jo][ks] = *reinterpret_cast<const bf16x8*>(
          &WdwB[(jo * 16 + (lane & 15)) * 64 + ks * 32 + (lane >> 4) * 8]);
  {
    int rr = tid >> 2, c0 = (tid & 3) * 16;
    const float* p0 = &ypart[(((size_t)b << 10) + n0 + rr) * 64 + c0];
    const float* p1 = p0 + ((size_t)32 << 16);  // ns=1 slab: 32*1024*64
#pragma unroll
    for (int h = 0; h < 2; ++h) {
      us8 pk;
#pragma unroll
      for (int q = 0; q < 2; ++q) {
        f32x4 v0 = *reinterpret_cast<const f32x4*>(p0 + h * 8 + q * 4);
        f32x4 v1 = *reinterpret_cast<const f32x4*>(p1 + h * 8 + q * 4);
#pragma unroll
        for (int e = 0; e < 4; ++e) pk[q * 4 + e] = f2b(lrelu(v0[e] + v1[e]));
      }
      *reinterpret_cast<us8*>(&YT[rr * 64 + ((((c0 >> 3) + h) ^ (rr & 7)) << 3)]) = pk;
    }
  }
  __syncthreads();
  f32x4 acc[4];
#pragma unroll
  for (int j = 0; j < 4; ++j) acc[j] = (f32x4){0.f, 0.f, 0.f, 0.f};
#pragma unroll
  for (int ks = 0; ks < 2; ++ks) {
    bf16x8 ay = fragr(YT, wave * 16 + (lane & 15), ks, lane);
#pragma unroll
    for (int jo = 0; jo < 4; ++jo)
      acc[jo] = __builtin_amdgcn_mfma_f32_16x16x32_bf16(ay, bw[jo][ks], acc[jo], 0, 0, 0);
  }
#pragma unroll
  for (int jo = 0; jo < 4; ++jo) {
    int o = jo * 16 + (lane & 15);
    float bs = bdw[o];
    f32x4 ov;
#pragma unroll
    for (int r = 0; r < 4; ++r) ov[r] = lrelu(acc[jo][r] + bs);
    *reinterpret_cast<f32x4*>(
        &dout[((size_t)(b * 64 + o) << 10) + n0 + wave * 16 + (lane >> 4) * 4]) = ov;
  }
}

extern "C" void kernel_launch(void* const* d_in, const int* in_sizes, int n_in,
                              void* d_out, int out_size, void* d_ws, size_t ws_size,
                              hipStream_t stream) {
  const float* x     = (const float*)d_in[0];
  const float* W_sa  = (const float*)d_in[1];
  const float* W_sw  = (const float*)d_in[2];
  const float* b_sw  = (const float*)d_in[3];
  const float* bn_g  = (const float*)d_in[4];
  const float* bn_b  = (const float*)d_in[5];
  const float* gamma = (const float*)d_in[6];
  const float* W_cm  = (const float*)d_in[7];
  const float* b_cm  = (const float*)d_in[8];
  const float* W_dw  = (const float*)d_in[9];
  const float* b_dw  = (const float*)d_in[10];
  float* out = (float*)d_out;

  char* ws = (char*)d_ws;
  const size_t MB = 1024 * 1024;
  unsigned short* xb    = (unsigned short*)(ws + 0 * MB);
  unsigned short* xbT   = (unsigned short*)(ws + 4 * MB);
  unsigned short* tT    = (unsigned short*)(ws + 8 * MB);
  unsigned short* x1b   = (unsigned short*)(ws + 12 * MB);
  unsigned short* xglbT = (unsigned short*)(ws + 16 * MB);
  unsigned short* WsaB  = (unsigned short*)(ws + 20 * MB);
  unsigned short* WcmB  = (unsigned short*)(ws + 22 * MB);
  unsigned short* WswB  = (unsigned short*)(ws + 22 * MB + 256 * 1024);
  unsigned short* WdwB  = (unsigned short*)(ws + 22 * MB + 288 * 1024);
  float*          en    = (float*)(ws + 23 * MB);
  unsigned short* attB  = (unsigned short*)(ws + 24 * MB);
  float*          ypart = (float*)(ws + 25 * MB);  // 16 MB

  prep_kernel<<<2084, 256, 0, stream>>>(x, W_sa, W_cm, W_sw, W_dw, xb, xbT, WsaB, WcmB, WswB, WdwB);
  energy_mfma<<<Bv, 256, 0, stream>>>(x, en);
  bn_att_kernel<<<Cv, 64, 0, stream>>>(en, bn_g, bn_b, attB);
  k1_gemm<<<dim3(16, Bv), 256, 0, stream>>>(xb, WsaB, tT);
  chanmix_mfma<0><<<dim3(16, Bv), 256, 0, stream>>>(tT, WswB, x, b_sw, nullptr, x1b);
  chanmix_mfma<1><<<dim3(16, Bv), 256, 0, stream>>>(xbT, attB, x, nullptr, gamma, xglbT);
  dyn_fused<<<dim3(16, Bv, 2), 256, 0, stream>>>(xglbT, x1b, WcmB, b_cm, ypart);
  final_gemm<<<dim3(16, Bv), 256, 0, stream>>>(ypart, WdwB, b_dw, out);
}

// Round 5
// 75.900 us; speedup vs baseline: 4.0715x; 1.3324x over previous
//
#include <hip/hip_runtime.h>

#define Bv 32
#define Cv 64
#define Nv 1024

typedef __attribute__((ext_vector_type(8))) short bf16x8;
typedef __attribute__((ext_vector_type(4))) float f32x4;
typedef __attribute__((ext_vector_type(8))) unsigned short us8;
typedef __attribute__((ext_vector_type(4))) unsigned short us4;

__device__ __forceinline__ float lrelu(float v) { return v >= 0.f ? v : 0.2f * v; }
__device__ __forceinline__ float sigmoidf_(float z) { return 1.f / (1.f + __expf(-z)); }
__device__ __forceinline__ unsigned short f2b(float f) {
  unsigned int u = __float_as_uint(f);
  unsigned int r = u + 0x7FFFu + ((u >> 16) & 1u);
  return (unsigned short)(r >> 16);
}
__device__ __forceinline__ void gload16(const void* g, void* l) {
  __builtin_amdgcn_global_load_lds((const __attribute__((address_space(1))) void*)g,
                                   (__attribute__((address_space(3))) void*)l, 16, 0, 0);
}
// 64x64 bf16 tile, linear LDS dest, XOR-swizzled global source; granule g of
// row r holds global granule g ^ (r&7). fragr applies the same XOR on read.
__device__ __forceinline__ void stage_tile(const unsigned short* src, size_t stride,
                                           unsigned short* dst, int wave, int lane) {
#pragma unroll
  for (int p = 0; p < 2; ++p) {
    int q = wave * 2 + p;
    int rr = q * 8 + (lane >> 3);
    int gS = ((lane & 7) ^ (rr & 7)) << 3;
    gload16(&src[(size_t)rr * stride + gS], &dst[q * 512]);
  }
}
__device__ __forceinline__ bf16x8 fragr(const unsigned short* buf, int row, int ks, int lane) {
  return *reinterpret_cast<const bf16x8*>(
      &buf[row * 64 + (((ks * 4 + (lane >> 4)) ^ (row & 7)) << 3)]);
}

// ---------------------------------------------------------------------------
// prep: all f32->bf16 conversions + xT transpose, one launch.
// ---------------------------------------------------------------------------
__device__ __forceinline__ void cvt8(const float* in, unsigned short* out, int i) {
  const f32x4* p = reinterpret_cast<const f32x4*>(in + (size_t)i * 8);
  f32x4 a = p[0], b = p[1];
  us8 o;
  o[0] = f2b(a[0]); o[1] = f2b(a[1]); o[2] = f2b(a[2]); o[3] = f2b(a[3]);
  o[4] = f2b(b[0]); o[5] = f2b(b[1]); o[6] = f2b(b[2]); o[7] = f2b(b[3]);
  *reinterpret_cast<us8*>(out + (size_t)i * 8) = o;
}

__global__ __launch_bounds__(256)
void prep_kernel(const float* __restrict__ x, const float* __restrict__ Wsa,
                 const float* __restrict__ Wcm, const float* __restrict__ Wsw,
                 const float* __restrict__ Wdw, unsigned short* __restrict__ xb,
                 unsigned short* __restrict__ xbT, unsigned short* __restrict__ WsaB,
                 unsigned short* __restrict__ WcmB, unsigned short* __restrict__ WswB,
                 unsigned short* __restrict__ WdwB) {
  __shared__ unsigned short L[64 * 72];
  const int blk = blockIdx.x, tid = threadIdx.x;
  if (blk < 1024) {
    cvt8(x, xb, blk * 256 + tid);
  } else if (blk < 1536) {
    int id = blk - 1024;
    int b = id >> 4, n0 = (id & 15) * 64;
    int c = tid >> 2, nseg = (tid & 3) * 16;
    const float* src = &x[((size_t)(b * 64 + c) << 10) + n0 + nseg];
#pragma unroll
    for (int q = 0; q < 4; ++q) {
      f32x4 v = *reinterpret_cast<const f32x4*>(src + q * 4);
#pragma unroll
      for (int e = 0; e < 4; ++e) L[(nseg + q * 4 + e) * 72 + c] = f2b(v[e]);
    }
    __syncthreads();
    int n = tid >> 2, cs = (tid & 3) * 16;
    us8 a = *reinterpret_cast<const us8*>(&L[n * 72 + cs]);
    us8 bq = *reinterpret_cast<const us8*>(&L[n * 72 + cs + 8]);
    unsigned short* dst = &xbT[(((size_t)b << 10) + n0 + n) * 64 + cs];
    *reinterpret_cast<us8*>(dst) = a;
    *reinterpret_cast<us8*>(dst + 8) = bq;
  } else if (blk < 2048) {
    cvt8(Wsa, WsaB, (blk - 1536) * 256 + tid);
  } else if (blk < 2080) {
    cvt8(Wcm, WcmB, (blk - 2048) * 256 + tid);
  } else if (blk < 2082) {
    cvt8(Wsw, WswB, (blk - 2080) * 256 + tid);
  } else {
    cvt8(Wdw, WdwB, (blk - 2082) * 256 + tid);
  }
}

// ---------------------------------------------------------------------------
// k1x1: fused  t = lrelu(x @ Wsa^T)  ->  x1 = x + lrelu(Wsw @ t + bsw)
// Block (n-tile, b): 64n x 64c output tile. 2-phase double-buffered staging.
// blockIdx.x==0 blocks also accumulate energy[b] = x[b] @ x[b]^T (As reuse).
// ---------------------------------------------------------------------------
__global__ __launch_bounds__(256)
void k1x1_kernel(const unsigned short* __restrict__ xb,
                 const unsigned short* __restrict__ WsaB,
                 const unsigned short* __restrict__ WswB,
                 const float* __restrict__ x, const float* __restrict__ bsw,
                 unsigned short* __restrict__ x1b, float* __restrict__ en) {
  __shared__ __align__(16) unsigned short As[2][4096];
  __shared__ __align__(16) unsigned short Bs[2][4096];
  __shared__ __align__(16) unsigned short TT[64 * 72];
  __shared__ __align__(16) float Xres[64 * 68];
  const int tid = threadIdx.x, wave = tid >> 6, lane = tid & 63;
  const int b = blockIdx.y, col0 = blockIdx.x * 64, row0 = b * 64;
  const int wr = wave >> 1, wc = wave & 1;
  const bool doEn = (blockIdx.x == 0);
  f32x4 acc[2][2], accE[4];
#pragma unroll
  for (int i = 0; i < 2; ++i)
#pragma unroll
    for (int j = 0; j < 2; ++j) acc[i][j] = (f32x4){0.f, 0.f, 0.f, 0.f};
#pragma unroll
  for (int j = 0; j < 4; ++j) accE[j] = (f32x4){0.f, 0.f, 0.f, 0.f};

  stage_tile(&xb[(size_t)row0 * Nv], Nv, As[0], wave, lane);
  stage_tile(&WsaB[(size_t)col0 * Nv], Nv, Bs[0], wave, lane);
  __syncthreads();
  for (int t = 0; t < 16; ++t) {
    const int cur = t & 1;
    if (t < 15) {
      stage_tile(&xb[(size_t)row0 * Nv + (t + 1) * 64], Nv, As[cur ^ 1], wave, lane);
      stage_tile(&WsaB[(size_t)col0 * Nv + (t + 1) * 64], Nv, Bs[cur ^ 1], wave, lane);
    }
#pragma unroll
    for (int ks = 0; ks < 2; ++ks) {
      bf16x8 af[2], bfg[2];
#pragma unroll
      for (int i = 0; i < 2; ++i) af[i] = fragr(As[cur], wr * 32 + i * 16 + (lane & 15), ks, lane);
#pragma unroll
      for (int j = 0; j < 2; ++j) bfg[j] = fragr(Bs[cur], wc * 32 + j * 16 + (lane & 15), ks, lane);
#pragma unroll
      for (int i = 0; i < 2; ++i)
#pragma unroll
        for (int j = 0; j < 2; ++j)
          acc[i][j] = __builtin_amdgcn_mfma_f32_16x16x32_bf16(af[i], bfg[j], acc[i][j], 0, 0, 0);
      if (doEn) {
        bf16x8 aE = fragr(As[cur], wave * 16 + (lane & 15), ks, lane);
#pragma unroll
        for (int j = 0; j < 4; ++j) {
          bf16x8 bE = fragr(As[cur], j * 16 + (lane & 15), ks, lane);
          accE[j] = __builtin_amdgcn_mfma_f32_16x16x32_bf16(aE, bE, accE[j], 0, 0, 0);
        }
      }
    }
    __syncthreads();
  }
  // t-tile -> TT [n][c] (stride 72, 2-way max on write & read)
#pragma unroll
  for (int i = 0; i < 2; ++i)
#pragma unroll
    for (int j = 0; j < 2; ++j) {
      us4 tv;
#pragma unroll
      for (int r = 0; r < 4; ++r) tv[r] = f2b(lrelu(acc[i][j][r]));
      *reinterpret_cast<us4*>(
          &TT[(wc * 32 + j * 16 + (lane & 15)) * 72 + wr * 32 + i * 16 + (lane >> 4) * 4]) = tv;
    }
  {  // residual x tile [o][n]
    int o = tid >> 2, ms = (tid & 3) * 16;
    const float* xs = &x[((size_t)(row0 + o) << 10) + col0 + ms];
#pragma unroll
    for (int q = 0; q < 4; ++q)
      *reinterpret_cast<f32x4*>(&Xres[o * 68 + ms + q * 4]) =
          *reinterpret_cast<const f32x4*>(xs + q * 4);
  }
  if (doEn) {
#pragma unroll
    for (int j = 0; j < 4; ++j)
#pragma unroll
      for (int r = 0; r < 4; ++r)
        en[(size_t)b * 4096 + (wave * 16 + (lane >> 4) * 4 + r) * 64 + j * 16 + (lane & 15)] =
            accE[j][r];
  }
  __syncthreads();
  // chanmix: x1[o][n] = x + lrelu(Wsw @ t + bsw)
  bf16x8 afw[2];
#pragma unroll
  for (int ks = 0; ks < 2; ++ks)
    afw[ks] = *reinterpret_cast<const bf16x8*>(
        &WswB[(wave * 16 + (lane & 15)) * 64 + ks * 32 + (lane >> 4) * 8]);
  f32x4 acc2[4];
#pragma unroll
  for (int j = 0; j < 4; ++j) acc2[j] = (f32x4){0.f, 0.f, 0.f, 0.f};
#pragma unroll
  for (int ks = 0; ks < 2; ++ks)
#pragma unroll
    for (int j = 0; j < 4; ++j) {
      bf16x8 bfr = *reinterpret_cast<const bf16x8*>(
          &TT[(j * 16 + (lane & 15)) * 72 + ks * 32 + (lane >> 4) * 8]);
      acc2[j] = __builtin_amdgcn_mfma_f32_16x16x32_bf16(afw[ks], bfr, acc2[j], 0, 0, 0);
    }
  f32x4 bs4 = *reinterpret_cast<const f32x4*>(&bsw[wave * 16 + (lane >> 4) * 4]);
#pragma unroll
  for (int j = 0; j < 4; ++j)
#pragma unroll
    for (int r = 0; r < 4; ++r) {
      int o = wave * 16 + (lane >> 4) * 4 + r;
      int nl = j * 16 + (lane & 15);
      x1b[((size_t)(row0 + o) << 10) + col0 + nl] =
          f2b(Xres[o * 68 + nl] + lrelu(acc2[j][r] + bs4[r]));
    }
}

// ---------------------------------------------------------------------------
// bn_att: attention = BN(rowmax(en) - en), bf16 out. One wave per channel c;
// m-e register-cached so en is read once.
// ---------------------------------------------------------------------------
__global__ __launch_bounds__(64)
void bn_att_kernel(const float* __restrict__ en, const float* __restrict__ bng,
                   const float* __restrict__ bnb, unsigned short* __restrict__ att) {
  const int c = blockIdx.x, d = threadIdx.x;
  float v[Bv];
  float sum = 0.f, sumsq = 0.f;
#pragma unroll
  for (int b = 0; b < Bv; ++b) {
    float e = en[(size_t)b * 4096 + c * 64 + d];
    float m = e;
#pragma unroll
    for (int o = 32; o > 0; o >>= 1) m = fmaxf(m, __shfl_xor(m, o));
    v[b] = m - e;
    sum += v[b]; sumsq += v[b] * v[b];
  }
#pragma unroll
  for (int o = 32; o > 0; o >>= 1) { sum += __shfl_xor(sum, o); sumsq += __shfl_xor(sumsq, o); }
  const float inv = 1.f / (float)(Bv * Cv);
  float mu = sum * inv;
  float var = sumsq * inv - mu * mu;
  float rs = rsqrtf(var + 1e-5f);
  float g = bng[c], be = bnb[c];
#pragma unroll
  for (int b = 0; b < Bv; ++b)
    att[(size_t)b * 4096 + c * 64 + d] = f2b(g * (v[b] - mu) * rs + be);
}

// ---------------------------------------------------------------------------
// dynmega: per block (m-tile, b):
//  head:  xglb[m][c] = gamma*(att[b] @ x[b]) + x   (MFMA, -> XG LDS)
//  loop:  S[n][m]=sigmoid(Wcm@xglb+bcm); accy[c][m] += x1 . S   (16 chunks, dbuf)
//  epi :  out[o][m] = lrelu(Wdw @ lrelu(accy) + bdw)
// LDS aliasing in buf[32768]: head {XB@0 (8KB), Xr@8192 (17KB)};
// loop {WT@cur*16384, X1@cur*16384+8192} (runtime-computed pointers — no
// static-initialized pointer arrays; gfx950 rejects addrspacecast initializers).
// ---------------------------------------------------------------------------
__global__ __launch_bounds__(256)
void dynmega_kernel(const unsigned short* __restrict__ xbT,
                    const unsigned short* __restrict__ x1b,
                    const unsigned short* __restrict__ attB,
                    const unsigned short* __restrict__ WcmB,
                    const unsigned short* __restrict__ WdwB,
                    const float* __restrict__ x, const float* __restrict__ bcm,
                    const float* __restrict__ bdw, const float* __restrict__ gamma_p,
                    float* __restrict__ dout) {
  __shared__ __align__(16) unsigned short XG[64 * 72];
  __shared__ __align__(16) char buf[32768];
  __shared__ __align__(16) unsigned short SBt[4 * 16 * 72];
  const int tid = threadIdx.x, wave = tid >> 6, lane = tid & 63;
  const int m0 = blockIdx.x * 64, b = blockIdx.y;
  // ---- head: stage xbT tile + x residual ----
  {
    unsigned short* XB = (unsigned short*)buf;
    float* Xr = (float*)(buf + 8192);
    stage_tile(&xbT[((size_t)b * 1024 + m0) * 64], 64, XB, wave, lane);
    {
      int o = tid >> 2, ms = (tid & 3) * 16;
      const float* xs = &x[((size_t)(b * 64 + o) << 10) + m0 + ms];
#pragma unroll
      for (int q = 0; q < 4; ++q)
        *reinterpret_cast<f32x4*>(&Xr[o * 68 + ms + q * 4]) =
            *reinterpret_cast<const f32x4*>(xs + q * 4);
    }
    __syncthreads();
    bf16x8 afA[2];
#pragma unroll
    for (int ks = 0; ks < 2; ++ks)
      afA[ks] = *reinterpret_cast<const bf16x8*>(
          &attB[(size_t)b * 4096 + (wave * 16 + (lane & 15)) * 64 + ks * 32 + (lane >> 4) * 8]);
    const float g0 = gamma_p[0];
#pragma unroll
    for (int j = 0; j < 4; ++j) {
      f32x4 ah = (f32x4){0.f, 0.f, 0.f, 0.f};
#pragma unroll
      for (int ks = 0; ks < 2; ++ks) {
        bf16x8 bfh = fragr(XB, j * 16 + (lane & 15), ks, lane);
        ah = __builtin_amdgcn_mfma_f32_16x16x32_bf16(afA[ks], bfh, ah, 0, 0, 0);
      }
      us4 gv;
#pragma unroll
      for (int r = 0; r < 4; ++r)
        gv[r] =
            f2b(g0 * ah[r] + Xr[(wave * 16 + (lane >> 4) * 4 + r) * 68 + j * 16 + (lane & 15)]);
      *reinterpret_cast<us4*>(
          &XG[(j * 16 + (lane & 15)) * 72 + wave * 16 + (lane >> 4) * 4]) = gv;
    }
  }
  __syncthreads();  // XG ready; XB/Xr reads done -> buf reusable
  bf16x8 xgf[2];
#pragma unroll
  for (int ks = 0; ks < 2; ++ks)
    xgf[ks] = *reinterpret_cast<const bf16x8*>(
        &XG[(wave * 16 + (lane & 15)) * 72 + ks * 32 + (lane >> 4) * 8]);
  stage_tile(&WcmB[0], 64, (unsigned short*)buf, wave, lane);
  stage_tile(&x1b[(size_t)b * 64 * 1024], 1024, (unsigned short*)(buf + 8192), wave, lane);
  __syncthreads();
  f32x4 accy[4];
#pragma unroll
  for (int j = 0; j < 4; ++j) accy[j] = (f32x4){0.f, 0.f, 0.f, 0.f};
  unsigned short* SB = &SBt[wave * 16 * 72];
  for (int ch = 0; ch < 16; ++ch) {
    const int cur = ch & 1;
    unsigned short* WTcur = (unsigned short*)(buf + cur * 16384);
    unsigned short* X1cur = (unsigned short*)(buf + cur * 16384 + 8192);
    if (ch < 15) {
      unsigned short* WTnxt = (unsigned short*)(buf + (cur ^ 1) * 16384);
      unsigned short* X1nxt = (unsigned short*)(buf + (cur ^ 1) * 16384 + 8192);
      stage_tile(&WcmB[(size_t)(ch + 1) * 64 * 64], 64, WTnxt, wave, lane);
      stage_tile(&x1b[(size_t)b * 64 * 1024 + (ch + 1) * 64], 1024, X1nxt, wave, lane);
    }
    // stage1: S[n][m-strip] = sigmoid(Wcm . xglb + bcm) -> SB (wave-private)
#pragma unroll
    for (int i = 0; i < 4; ++i) {
      f32x4 s = (f32x4){0.f, 0.f, 0.f, 0.f};
#pragma unroll
      for (int ks = 0; ks < 2; ++ks) {
        bf16x8 af = fragr(WTcur, i * 16 + (lane & 15), ks, lane);
        s = __builtin_amdgcn_mfma_f32_16x16x32_bf16(af, xgf[ks], s, 0, 0, 0);
      }
      f32x4 bc4 = *reinterpret_cast<const f32x4*>(&bcm[ch * 64 + i * 16 + (lane >> 4) * 4]);
      us4 sv;
#pragma unroll
      for (int r = 0; r < 4; ++r) sv[r] = f2b(sigmoidf_(s[r] + bc4[r]));
      *reinterpret_cast<us4*>(&SB[(lane & 15) * 72 + i * 16 + (lane >> 4) * 4]) = sv;
    }
    // stage2: accy[c][m-strip] += x1 . S
#pragma unroll
    for (int ks = 0; ks < 2; ++ks) {
      bf16x8 b2 = *reinterpret_cast<const bf16x8*>(
          &SB[(lane & 15) * 72 + ks * 32 + (lane >> 4) * 8]);
#pragma unroll
      for (int jc = 0; jc < 4; ++jc) {
        bf16x8 a2 = fragr(X1cur, jc * 16 + (lane & 15), ks, lane);
        accy[jc] = __builtin_amdgcn_mfma_f32_16x16x32_bf16(a2, b2, accy[jc], 0, 0, 0);
      }
    }
    __syncthreads();
  }
  // epilogue: y1 = lrelu(accy) -> YT [m][c] (reuse SB strip); out = lrelu(Wdw@y1+bdw)
  unsigned short* YT = SB;
#pragma unroll
  for (int jc = 0; jc < 4; ++jc) {
    us4 yv;
#pragma unroll
    for (int r = 0; r < 4; ++r) yv[r] = f2b(lrelu(accy[jc][r]));
    *reinterpret_cast<us4*>(&YT[(lane & 15) * 72 + jc * 16 + (lane >> 4) * 4]) = yv;
  }
  bf16x8 afW[4][2];
#pragma unroll
  for (int jo = 0; jo < 4; ++jo)
#pragma unroll
    for (int ks = 0; ks < 2; ++ks)
      afW[jo][ks] = *reinterpret_cast<const bf16x8*>(
          &WdwB[(jo * 16 + (lane & 15)) * 64 + ks * 32 + (lane >> 4) * 8]);
  f32x4 accf[4];
#pragma unroll
  for (int j = 0; j < 4; ++j) accf[j] = (f32x4){0.f, 0.f, 0.f, 0.f};
#pragma unroll
  for (int ks = 0; ks < 2; ++ks) {
    bf16x8 yf = *reinterpret_cast<const bf16x8*>(
        &YT[(lane & 15) * 72 + ks * 32 + (lane >> 4) * 8]);
#pragma unroll
    for (int jo = 0; jo < 4; ++jo)
      accf[jo] = __builtin_amdgcn_mfma_f32_16x16x32_bf16(afW[jo][ks], yf, accf[jo], 0, 0, 0);
  }
#pragma unroll
  for (int jo = 0; jo < 4; ++jo) {
    f32x4 bs4 = *reinterpret_cast<const f32x4*>(&bdw[jo * 16 + (lane >> 4) * 4]);
#pragma unroll
    for (int r = 0; r < 4; ++r) {
      int o = jo * 16 + (lane >> 4) * 4 + r;
      dout[((size_t)(b * 64 + o) << 10) + m0 + wave * 16 + (lane & 15)] =
          lrelu(accf[jo][r] + bs4[r]);
    }
  }
}

extern "C" void kernel_launch(void* const* d_in, const int* in_sizes, int n_in,
                              void* d_out, int out_size, void* d_ws, size_t ws_size,
                              hipStream_t stream) {
  const float* x     = (const float*)d_in[0];
  const float* W_sa  = (const float*)d_in[1];
  const float* W_sw  = (const float*)d_in[2];
  const float* b_sw  = (const float*)d_in[3];
  const float* bn_g  = (const float*)d_in[4];
  const float* bn_b  = (const float*)d_in[5];
  const float* gamma = (const float*)d_in[6];
  const float* W_cm  = (const float*)d_in[7];
  const float* b_cm  = (const float*)d_in[8];
  const float* W_dw  = (const float*)d_in[9];
  const float* b_dw  = (const float*)d_in[10];
  float* out = (float*)d_out;

  char* ws = (char*)d_ws;
  const size_t MB = 1024 * 1024;
  unsigned short* xb   = (unsigned short*)(ws + 0 * MB);    // 4MB
  unsigned short* xbT  = (unsigned short*)(ws + 4 * MB);    // 4MB
  unsigned short* WsaB = (unsigned short*)(ws + 8 * MB);    // 2MB
  unsigned short* WcmB = (unsigned short*)(ws + 10 * MB);   // 128KB
  unsigned short* WswB = (unsigned short*)(ws + 10 * MB + 256 * 1024);  // 8KB
  unsigned short* WdwB = (unsigned short*)(ws + 10 * MB + 288 * 1024);  // 8KB
  unsigned short* x1b  = (unsigned short*)(ws + 11 * MB);   // 4MB
  float*          en   = (float*)(ws + 15 * MB);            // 512KB
  unsigned short* attB = (unsigned short*)(ws + 16 * MB);   // 8KB

  prep_kernel<<<2084, 256, 0, stream>>>(x, W_sa, W_cm, W_sw, W_dw, xb, xbT, WsaB, WcmB, WswB, WdwB);
  k1x1_kernel<<<dim3(16, Bv), 256, 0, stream>>>(xb, WsaB, WswB, x, b_sw, x1b, en);
  bn_att_kernel<<<Cv, 64, 0, stream>>>(en, bn_g, bn_b, attB);
  dynmega_kernel<<<dim3(16, Bv), 256, 0, stream>>>(xbT, x1b, attB, WcmB, WdwB, x, b_cm, b_dw,
                                                   gamma, out);
}